// Round 10
// baseline (7735.258 us; speedup 1.0000x reference)
//
#include <hip/hip_runtime.h>
#include <stdint.h>

#define BB   64
#define TT   512
#define KIN  256
#define HH   512
#define NBLK 64      // j-slices (8 columns of H each)
#define NJ   8

typedef short bf16x8 __attribute__((ext_vector_type(8)));
typedef float f32x4  __attribute__((ext_vector_type(4)));

union U16x8 { unsigned short s[8]; bf16x8 v; };
union FU    { float f; unsigned u; };

__device__ __forceinline__ unsigned short f2bf(float f){
  FU v; v.f = f;
  unsigned r = v.u + 0x7fffu + ((v.u >> 16) & 1u);   // RNE
  return (unsigned short)(r >> 16);
}
__device__ __forceinline__ float bf2f(unsigned short s){
  FU v; v.u = ((unsigned)s) << 16; return v.f;
}
__device__ __forceinline__ bf16x8 zfrag(){
  U16x8 z;
  #pragma unroll
  for(int i=0;i<8;i++) z.s[i]=0;
  return z.v;
}
// 8 consecutive f32 -> split bf16 hi/lo fragments
__device__ __forceinline__ void split8(const float* p, bf16x8& hi, bf16x8& lo){
  float4 a = ((const float4*)p)[0];
  float4 b = ((const float4*)p)[1];
  float f[8] = {a.x,a.y,a.z,a.w,b.x,b.y,b.z,b.w};
  U16x8 h,l;
  #pragma unroll
  for(int i=0;i<8;i++){
    unsigned short hb = f2bf(f[i]);
    l.s[i] = f2bf(f[i] - bf2f(hb));
    h.s[i] = hb;
  }
  hi = h.v; lo = l.v;
}
// two uint4 (8 packed u32 words, bf16hi|bf16lo) -> hi/lo fragments
__device__ __forceinline__ void unpackg(uint4 A, uint4 B, bf16x8& hi, bf16x8& lo){
  unsigned wv[8] = {A.x,A.y,A.z,A.w,B.x,B.y,B.z,B.w};
  U16x8 h,l;
  #pragma unroll
  for(int j=0;j<8;j++){
    h.s[j] = (unsigned short)(wv[j] >> 16);
    l.s[j] = (unsigned short)(wv[j] & 0xffffu);
  }
  hi = h.v; lo = l.v;
}

#define MFMA __builtin_amdgcn_mfma_f32_16x16x32_bf16

// SELF-CONTAINED coherent load of both rows' k-quarter slices:
// 16 x dwordx4 sc1 + vmcnt(0) drain in ONE asm block (values ready at exit).
#define LD16W(G0,G1,G2,G3,G4,G5,G6,G7,G8,G9,Ga,Gb,Gc,Gd,Ge,Gf, B0, B1) \
  asm volatile( \
    "global_load_dwordx4 %0, %16, off sc1\n\t" \
    "global_load_dwordx4 %1, %16, off offset:16 sc1\n\t" \
    "global_load_dwordx4 %2, %16, off offset:128 sc1\n\t" \
    "global_load_dwordx4 %3, %16, off offset:144 sc1\n\t" \
    "global_load_dwordx4 %4, %16, off offset:256 sc1\n\t" \
    "global_load_dwordx4 %5, %16, off offset:272 sc1\n\t" \
    "global_load_dwordx4 %6, %16, off offset:384 sc1\n\t" \
    "global_load_dwordx4 %7, %16, off offset:400 sc1\n\t" \
    "global_load_dwordx4 %8, %17, off sc1\n\t" \
    "global_load_dwordx4 %9, %17, off offset:16 sc1\n\t" \
    "global_load_dwordx4 %10, %17, off offset:128 sc1\n\t" \
    "global_load_dwordx4 %11, %17, off offset:144 sc1\n\t" \
    "global_load_dwordx4 %12, %17, off offset:256 sc1\n\t" \
    "global_load_dwordx4 %13, %17, off offset:272 sc1\n\t" \
    "global_load_dwordx4 %14, %17, off offset:384 sc1\n\t" \
    "global_load_dwordx4 %15, %17, off offset:400 sc1\n\t" \
    "s_waitcnt vmcnt(0)" \
    : "=&v"(G0),"=&v"(G1),"=&v"(G2),"=&v"(G3),"=&v"(G4),"=&v"(G5),"=&v"(G6),"=&v"(G7), \
      "=&v"(G8),"=&v"(G9),"=&v"(Ga),"=&v"(Gb),"=&v"(Gc),"=&v"(Gd),"=&v"(Ge),"=&v"(Gf) \
    : "v"(B0), "v"(B1) : "memory")

__global__ __launch_bounds__(512, 2) void gru_scan(
    const float* __restrict__ x,  const float* __restrict__ Wm,
    const float* __restrict__ bW, const float* __restrict__ Um,
    const float* __restrict__ bU, float* __restrict__ out,
    unsigned* __restrict__ hbuf,  unsigned* __restrict__ flags)
{
  __shared__ f32x4 red [4][4][2][64];   // [q][mt][nt][lane] h-gate reduce (32 KB)
  __shared__ f32x4 red2[4][4][2][64];   // xg reduce (32 KB)
  __shared__ unsigned sctr;             // gate-wave arrival counter (monotone)

  const int tid  = threadIdx.x;
  const int u    = tid >> 6;        // wave 0..7
  const int q    = u >> 1;          // k-quarter
  const int m2   = u & 1;           // mt-pair: mt in {2*m2, 2*m2+1}
  const int lane = tid & 63;
  const int col  = lane & 15;
  const int lg   = lane >> 4;
  const int j0   = blockIdx.x * NJ;
  const int bid  = blockIdx.x;

  if(tid == 0) sctr = 0u;

  // ---- persistent U/W fragments for k-quarter q (split bf16, registers) ----
  bf16x8 BUhi[2][4], BUlo[2][4], BWhi[2][2], BWlo[2][2];
  #pragma unroll
  for(int nt=0; nt<2; nt++){
    int rl    = nt*16 + col;          // local row 0..31 (24 valid)
    int valid = rl < 24;
    int g     = rl >> 3, jj = rl & 7;
    int grow  = g*HH + j0 + jj;       // row in [3H]
    #pragma unroll
    for(int ks=0; ks<4; ks++){
      int kb = q*128 + ks*32 + lg*8;
      if(valid) split8(Um + (size_t)grow*HH + kb, BUhi[nt][ks], BUlo[nt][ks]);
      else { BUhi[nt][ks]=zfrag(); BUlo[nt][ks]=zfrag(); }
    }
    #pragma unroll
    for(int ks=0; ks<2; ks++){
      int kb = q*64 + ks*32 + lg*8;
      if(valid) split8(Wm + (size_t)grow*KIN + kb, BWhi[nt][ks], BWlo[nt][ks]);
      else { BWhi[nt][ks]=zfrag(); BWlo[nt][ks]=zfrag(); }
    }
  }

  // ---- biases for this lane's gate rows (gate waves u<4) ----
  float bsum0, bwn, bun;
  {
    int r0 = (col < 8) ? (j0 + col) : (HH + j0 + col - 8);
    bsum0 = bW[r0] + bU[r0];
    int rn = 2*HH + j0 + (col & 7);
    bwn = bW[rn]; bun = bU[rn];
  }

  float hreg[4] = {0.f,0.f,0.f,0.f};

  // ---- poll barrier: ONLY wave 7 polls (64 pollers chip-wide, not 512) ----
  auto pollbar = [&](int cell){
    if(u == 7){
      const unsigned tgt = (unsigned)cell;
      while(true){
        unsigned f = __hip_atomic_load(&flags[lane], __ATOMIC_RELAXED,
                                       __HIP_MEMORY_SCOPE_AGENT);
        if(__all((int)(f >= tgt))) break;
        __builtin_amdgcn_s_sleep(1);
      }
    }
    __builtin_amdgcn_s_barrier();
    __builtin_amdgcn_sched_barrier(0);
  };

  // ---- xg partials only (MFMA + red2 write, NO sync) ----
  auto xg_partials = [&](int tt){
    f32x4 Cx[2][2];
    #pragma unroll
    for(int mi=0;mi<2;mi++){ Cx[mi][0]=(f32x4){0,0,0,0}; Cx[mi][1]=(f32x4){0,0,0,0}; }
    #pragma unroll
    for(int mi=0; mi<2; mi++){
      int mt = 2*m2 + mi, b = mt*16 + col;
      #pragma unroll
      for(int ks=0; ks<2; ks++){
        int kb = q*64 + ks*32 + lg*8;
        bf16x8 ah, al; split8(x + ((size_t)b*TT + tt)*KIN + kb, ah, al);
        #pragma unroll
        for(int nt=0; nt<2; nt++){
          Cx[mi][nt] = MFMA(ah, BWhi[nt][ks], Cx[mi][nt], 0,0,0);
          Cx[mi][nt] = MFMA(ah, BWlo[nt][ks], Cx[mi][nt], 0,0,0);
          Cx[mi][nt] = MFMA(al, BWhi[nt][ks], Cx[mi][nt], 0,0,0);
        }
      }
    }
    #pragma unroll
    for(int mi=0;mi<2;mi++)
      #pragma unroll
      for(int nt=0;nt<2;nt++)
        red2[q][2*m2+mi][nt][lane] = Cx[mi][nt];
  };

  // ---- h exchange + MFMA partials into red (consumer side of a cell) ----
  auto h_mfma = [&](const unsigned* hb){
    int b0 = (2*m2+0)*16 + col, b1 = (2*m2+1)*16 + col;
    const void* a0 = (const char*)(hb + (size_t)b0*HH + q*128 + lg*8);
    const void* a1 = (const char*)(hb + (size_t)b1*HH + q*128 + lg*8);
    uint4 g00,g01,g02,g03,g04,g05,g06,g07,g10,g11,g12,g13,g14,g15,g16,g17;
    LD16W(g00,g01,g02,g03,g04,g05,g06,g07,
          g10,g11,g12,g13,g14,g15,g16,g17, a0, a1);
    __builtin_amdgcn_sched_barrier(0);

    f32x4 Ch[2][2];
    #pragma unroll
    for(int mi=0;mi<2;mi++){ Ch[mi][0]=(f32x4){0,0,0,0}; Ch[mi][1]=(f32x4){0,0,0,0}; }
    {
      bf16x8 ah, al;
      unpackg(g00,g01,ah,al);
      #pragma unroll
      for(int nt=0;nt<2;nt++){ Ch[0][nt]=MFMA(ah,BUhi[nt][0],Ch[0][nt],0,0,0); Ch[0][nt]=MFMA(ah,BUlo[nt][0],Ch[0][nt],0,0,0); Ch[0][nt]=MFMA(al,BUhi[nt][0],Ch[0][nt],0,0,0); }
      unpackg(g02,g03,ah,al);
      #pragma unroll
      for(int nt=0;nt<2;nt++){ Ch[0][nt]=MFMA(ah,BUhi[nt][1],Ch[0][nt],0,0,0); Ch[0][nt]=MFMA(ah,BUlo[nt][1],Ch[0][nt],0,0,0); Ch[0][nt]=MFMA(al,BUhi[nt][1],Ch[0][nt],0,0,0); }
      unpackg(g04,g05,ah,al);
      #pragma unroll
      for(int nt=0;nt<2;nt++){ Ch[0][nt]=MFMA(ah,BUhi[nt][2],Ch[0][nt],0,0,0); Ch[0][nt]=MFMA(ah,BUlo[nt][2],Ch[0][nt],0,0,0); Ch[0][nt]=MFMA(al,BUhi[nt][2],Ch[0][nt],0,0,0); }
      unpackg(g06,g07,ah,al);
      #pragma unroll
      for(int nt=0;nt<2;nt++){ Ch[0][nt]=MFMA(ah,BUhi[nt][3],Ch[0][nt],0,0,0); Ch[0][nt]=MFMA(ah,BUlo[nt][3],Ch[0][nt],0,0,0); Ch[0][nt]=MFMA(al,BUhi[nt][3],Ch[0][nt],0,0,0); }
      unpackg(g10,g11,ah,al);
      #pragma unroll
      for(int nt=0;nt<2;nt++){ Ch[1][nt]=MFMA(ah,BUhi[nt][0],Ch[1][nt],0,0,0); Ch[1][nt]=MFMA(ah,BUlo[nt][0],Ch[1][nt],0,0,0); Ch[1][nt]=MFMA(al,BUhi[nt][0],Ch[1][nt],0,0,0); }
      unpackg(g12,g13,ah,al);
      #pragma unroll
      for(int nt=0;nt<2;nt++){ Ch[1][nt]=MFMA(ah,BUhi[nt][1],Ch[1][nt],0,0,0); Ch[1][nt]=MFMA(ah,BUlo[nt][1],Ch[1][nt],0,0,0); Ch[1][nt]=MFMA(al,BUhi[nt][1],Ch[1][nt],0,0,0); }
      unpackg(g14,g15,ah,al);
      #pragma unroll
      for(int nt=0;nt<2;nt++){ Ch[1][nt]=MFMA(ah,BUhi[nt][2],Ch[1][nt],0,0,0); Ch[1][nt]=MFMA(ah,BUlo[nt][2],Ch[1][nt],0,0,0); Ch[1][nt]=MFMA(al,BUhi[nt][2],Ch[1][nt],0,0,0); }
      unpackg(g16,g17,ah,al);
      #pragma unroll
      for(int nt=0;nt<2;nt++){ Ch[1][nt]=MFMA(ah,BUhi[nt][3],Ch[1][nt],0,0,0); Ch[1][nt]=MFMA(ah,BUlo[nt][3],Ch[1][nt],0,0,0); Ch[1][nt]=MFMA(al,BUhi[nt][3],Ch[1][nt],0,0,0); }
    }
    #pragma unroll
    for(int mi=0;mi<2;mi++)
      #pragma unroll
      for(int nt=0;nt<2;nt++)
        red[q][2*m2+mi][nt][lane] = Ch[mi][nt];
  };

  // ---- gate phase (u<4): reduce red, gates, h-store, drain, publish, out ----
  auto gates = [&](int cell, unsigned* hw, const f32x4 (&xgf)[2]){
    const int w = u;
    f32x4 hgf[2];
    #pragma unroll
    for(int nt=0; nt<2; nt++)
      hgf[nt] = red[0][w][nt][lane] + red[1][w][nt][lane]
              + red[2][w][nt][lane] + red[3][w][nt][lane];
    float p0[4], p0s[4];
    #pragma unroll
    for(int r=0;r<4;r++) p0[r] = xgf[0][r] + hgf[0][r] + bsum0;
    #pragma unroll
    for(int r=0;r<4;r++) p0s[r] = __shfl_xor(p0[r], 8, 64);
    float hn4[4] = {0,0,0,0};
    if(col < 8){
      #pragma unroll
      for(int r=0;r<4;r++){
        int b = w*16 + lg*4 + r;
        float rg = __builtin_amdgcn_rcpf(1.f + __expf(-p0[r]));
        float ug = __builtin_amdgcn_rcpf(1.f + __expf(-p0s[r]));
        float hn = hgf[1][r] + bun;
        float z  = xgf[1][r] + bwn + rg*hn;
        z = fminf(fmaxf(z, -15.f), 15.f);
        float e  = __expf(2.f*z);
        float nn = (e - 1.f) * __builtin_amdgcn_rcpf(e + 1.f);   // tanh(z)
        float hnew = ug*hreg[r] + (1.f - ug)*nn;
        hreg[r] = hnew;
        hn4[r]  = hnew;
        unsigned short h16 = f2bf(hnew);
        unsigned short l16 = f2bf(hnew - bf2f(h16));
        __hip_atomic_store(&hw[(size_t)b*HH + j0 + col],
                           ((unsigned)h16 << 16) | (unsigned)l16,
                           __ATOMIC_RELAXED, __HIP_MEMORY_SCOPE_AGENT);
      }
    }
    // drain h-stores to LLC, then last gate wave publishes the flag
    asm volatile("s_waitcnt vmcnt(0)" ::: "memory");
    if(lane == 0){
      unsigned old = __hip_atomic_fetch_add(&sctr, 1u, __ATOMIC_RELAXED,
                                            __HIP_MEMORY_SCOPE_WORKGROUP);
      if(old == 4u*(unsigned)cell + 3u)
        __hip_atomic_store(&flags[bid], (unsigned)cell + 1u,
                           __ATOMIC_RELAXED, __HIP_MEMORY_SCOPE_AGENT);
    }
    // out-stores off the critical path
    if(col < 8){
      #pragma unroll
      for(int r=0;r<4;r++){
        int b = w*16 + lg*4 + r;
        out[((size_t)cell*BB + b)*HH + j0 + col] = hn4[r];
      }
    }
  };

  unsigned* hb0 = hbuf;
  unsigned* hb1 = hbuf + (size_t)BB*HH;

  f32x4 xgf[2] = {(f32x4){0,0,0,0},(f32x4){0,0,0,0}};
  f32x4 xgn[2] = {(f32x4){0,0,0,0},(f32x4){0,0,0,0}};

  // prologue: xg(0)
  xg_partials(0);
  __syncthreads();
  if(u < 4){
    #pragma unroll
    for(int nt=0; nt<2; nt++)
      xgf[nt] = red2[0][u][nt][lane] + red2[1][u][nt][lane]
              + red2[2][u][nt][lane] + red2[3][u][nt][lane];
  }

  for(int t=0; t<TT; t++){
    const int c0 = 2*t;
    // ---- even cell: read buf0, write buf1 ----
    pollbar(c0);
    h_mfma(hb0);
    __syncthreads();
    if(u < 4) gates(c0, hb1, xgf);
    // overlap publish propagation with next timestep's xg partials
    if(t+1 < TT) xg_partials(t+1);
    // ---- odd cell: read buf1, write buf0 ----
    pollbar(c0+1);
    h_mfma(hb1);
    __syncthreads();          // covers red AND red2
    if(u < 4){
      if(t+1 < TT){
        #pragma unroll
        for(int nt=0; nt<2; nt++)
          xgn[nt] = red2[0][u][nt][lane] + red2[1][u][nt][lane]
                  + red2[2][u][nt][lane] + red2[3][u][nt][lane];
      }
      gates(c0+1, hb0, xgf);
    }
    xgf[0] = xgn[0]; xgf[1] = xgn[1];
  }
}

extern "C" void kernel_launch(void* const* d_in, const int* in_sizes, int n_in,
                              void* d_out, int out_size, void* d_ws, size_t ws_size,
                              hipStream_t stream) {
  const float* x  = (const float*)d_in[0];
  const float* Wm = (const float*)d_in[1];
  const float* bW = (const float*)d_in[2];
  const float* Um = (const float*)d_in[3];
  const float* bU = (const float*)d_in[4];
  float* out = (float*)d_out;

  // ws layout: hbuf[2][64][512] u32 (256 KB) + flags[64] u32
  unsigned* hbuf  = (unsigned*)d_ws;
  unsigned* flags = (unsigned*)((char*)d_ws + 2*BB*HH*sizeof(unsigned));
  (void)hipMemsetAsync(d_ws, 0, 2*BB*HH*sizeof(unsigned) + 256, stream);

  gru_scan<<<NBLK, 512, 0, stream>>>(x, Wm, bW, Um, bU, out, hbuf, flags);
}

// Round 12
// 6103.665 us; speedup vs baseline: 1.2673x; 1.2673x over previous
//
#include <hip/hip_runtime.h>
#include <stdint.h>

#define BB   64
#define TT   512
#define KIN  256
#define HH   512
#define NBLK 64      // j-slices (8 columns of H each)
#define NJ   8
#define XPAD 260     // 256 + 4 floats: breaks LDS bank conflict (row stride 1040B)

typedef short bf16x8 __attribute__((ext_vector_type(8)));
typedef float f32x4  __attribute__((ext_vector_type(4)));

union U16x8 { unsigned short s[8]; bf16x8 v; };
union FU    { float f; unsigned u; };

__device__ __forceinline__ unsigned short f2bf(float f){
  FU v; v.f = f;
  unsigned r = v.u + 0x7fffu + ((v.u >> 16) & 1u);   // RNE
  return (unsigned short)(r >> 16);
}
__device__ __forceinline__ float bf2f(unsigned short s){
  FU v; v.u = ((unsigned)s) << 16; return v.f;
}
__device__ __forceinline__ bf16x8 zfrag(){
  U16x8 z;
  #pragma unroll
  for(int i=0;i<8;i++) z.s[i]=0;
  return z.v;
}
// 8 consecutive f32 -> split bf16 hi/lo fragments
__device__ __forceinline__ void split8(const float* p, bf16x8& hi, bf16x8& lo){
  float4 a = ((const float4*)p)[0];
  float4 b = ((const float4*)p)[1];
  float f[8] = {a.x,a.y,a.z,a.w,b.x,b.y,b.z,b.w};
  U16x8 h,l;
  #pragma unroll
  for(int i=0;i<8;i++){
    unsigned short hb = f2bf(f[i]);
    l.s[i] = f2bf(f[i] - bf2f(hb));
    h.s[i] = hb;
  }
  hi = h.v; lo = l.v;
}
// two uint4 (8 packed u32 words, bf16hi|bf16lo) -> hi/lo fragments
__device__ __forceinline__ void unpackg(uint4 A, uint4 B, bf16x8& hi, bf16x8& lo){
  unsigned wv[8] = {A.x,A.y,A.z,A.w,B.x,B.y,B.z,B.w};
  U16x8 h,l;
  #pragma unroll
  for(int j=0;j<8;j++){
    h.s[j] = (unsigned short)(wv[j] >> 16);
    l.s[j] = (unsigned short)(wv[j] & 0xffffu);
  }
  hi = h.v; lo = l.v;
}

#define MFMA __builtin_amdgcn_mfma_f32_16x16x32_bf16

// SELF-CONTAINED coherent load of both rows' k-quarter slices:
// 16 x dwordx4 sc1 + vmcnt(0) drain in ONE asm block (values ready at exit).
#define LD16W(G0,G1,G2,G3,G4,G5,G6,G7,G8,G9,Ga,Gb,Gc,Gd,Ge,Gf, B0, B1) \
  asm volatile( \
    "global_load_dwordx4 %0, %16, off sc1\n\t" \
    "global_load_dwordx4 %1, %16, off offset:16 sc1\n\t" \
    "global_load_dwordx4 %2, %16, off offset:128 sc1\n\t" \
    "global_load_dwordx4 %3, %16, off offset:144 sc1\n\t" \
    "global_load_dwordx4 %4, %16, off offset:256 sc1\n\t" \
    "global_load_dwordx4 %5, %16, off offset:272 sc1\n\t" \
    "global_load_dwordx4 %6, %16, off offset:384 sc1\n\t" \
    "global_load_dwordx4 %7, %16, off offset:400 sc1\n\t" \
    "global_load_dwordx4 %8, %17, off sc1\n\t" \
    "global_load_dwordx4 %9, %17, off offset:16 sc1\n\t" \
    "global_load_dwordx4 %10, %17, off offset:128 sc1\n\t" \
    "global_load_dwordx4 %11, %17, off offset:144 sc1\n\t" \
    "global_load_dwordx4 %12, %17, off offset:256 sc1\n\t" \
    "global_load_dwordx4 %13, %17, off offset:272 sc1\n\t" \
    "global_load_dwordx4 %14, %17, off offset:384 sc1\n\t" \
    "global_load_dwordx4 %15, %17, off offset:400 sc1\n\t" \
    "s_waitcnt vmcnt(0)" \
    : "=&v"(G0),"=&v"(G1),"=&v"(G2),"=&v"(G3),"=&v"(G4),"=&v"(G5),"=&v"(G6),"=&v"(G7), \
      "=&v"(G8),"=&v"(G9),"=&v"(Ga),"=&v"(Gb),"=&v"(Gc),"=&v"(Gd),"=&v"(Ge),"=&v"(Gf) \
    : "v"(B0), "v"(B1) : "memory")

__global__ __launch_bounds__(512, 1) void gru_scan(
    const float* __restrict__ x,  const float* __restrict__ Wm,
    const float* __restrict__ bW, const float* __restrict__ Um,
    const float* __restrict__ bU, float* __restrict__ out,
    unsigned* __restrict__ hbuf,  unsigned* __restrict__ flags)
{
  __shared__ f32x4 red [4][4][2][64];   // [q][mt][nt][lane] h-gate reduce (32 KB)
  __shared__ f32x4 red2[4][4][2][64];   // xg reduce (32 KB)
  __shared__ float xlds[BB][XPAD];      // x(t) staging, padded rows (65 KB)

  const int tid  = threadIdx.x;
  const int u    = tid >> 6;        // wave 0..7
  const int q    = u >> 1;          // k-quarter
  const int m2   = u & 1;           // mt-pair: mt in {2*m2, 2*m2+1}
  const int lane = tid & 63;
  const int col  = lane & 15;
  const int lg   = lane >> 4;
  const int j0   = blockIdx.x * NJ;
  const int bid  = blockIdx.x;

  // ---- persistent U/W fragments for k-quarter q (split bf16, registers) ----
  bf16x8 BUhi[2][4], BUlo[2][4], BWhi[2][2], BWlo[2][2];
  #pragma unroll
  for(int nt=0; nt<2; nt++){
    int rl    = nt*16 + col;          // local row 0..31 (24 valid)
    int valid = rl < 24;
    int g     = rl >> 3, jj = rl & 7;
    int grow  = g*HH + j0 + jj;       // row in [3H]
    #pragma unroll
    for(int ks=0; ks<4; ks++){
      int kb = q*128 + ks*32 + lg*8;
      if(valid) split8(Um + (size_t)grow*HH + kb, BUhi[nt][ks], BUlo[nt][ks]);
      else { BUhi[nt][ks]=zfrag(); BUlo[nt][ks]=zfrag(); }
    }
    #pragma unroll
    for(int ks=0; ks<2; ks++){
      int kb = q*64 + ks*32 + lg*8;
      if(valid) split8(Wm + (size_t)grow*KIN + kb, BWhi[nt][ks], BWlo[nt][ks]);
      else { BWhi[nt][ks]=zfrag(); BWlo[nt][ks]=zfrag(); }
    }
  }

  // ---- biases for this lane's gate rows (gate waves u<4) ----
  float bsum0, bwn, bun;
  {
    int r0 = (col < 8) ? (j0 + col) : (HH + j0 + col - 8);
    bsum0 = bW[r0] + bU[r0];
    int rn = 2*HH + j0 + (col & 7);
    bwn = bW[rn]; bun = bU[rn];
  }

  float hreg[4] = {0.f,0.f,0.f,0.f};
  unsigned bar = 0;

  // ---- stage x(tt) into LDS: wave u loads rows u*8..u*8+7 ----
  // global src is PER-LANE (gp + lane*16B); LDS dst is uniform base + lane*16B
  auto stage_x = [&](int tt){
    #pragma unroll
    for(int i=0; i<8; i++){
      int b = u*8 + i;
      const float* gp = x + ((size_t)b*TT + tt)*KIN + lane*4;
      __builtin_amdgcn_global_load_lds(
        (const __attribute__((address_space(1))) unsigned*)(const void*)gp,
        (__attribute__((address_space(3))) unsigned*)(void*)&xlds[b][0],
        16, 0, 0);
    }
  };

  // ---- xg partials from LDS x + cross-wave reduce (red2) ----
  auto xg_partials = [&](){
    f32x4 Cx[2][2];
    #pragma unroll
    for(int mi=0;mi<2;mi++){ Cx[mi][0]=(f32x4){0,0,0,0}; Cx[mi][1]=(f32x4){0,0,0,0}; }
    #pragma unroll
    for(int mi=0; mi<2; mi++){
      int mt = 2*m2 + mi, b = mt*16 + col;
      #pragma unroll
      for(int ks=0; ks<2; ks++){
        int kb = q*64 + ks*32 + lg*8;
        bf16x8 ah, al; split8(&xlds[b][kb], ah, al);
        #pragma unroll
        for(int nt=0; nt<2; nt++){
          Cx[mi][nt] = MFMA(ah, BWhi[nt][ks], Cx[mi][nt], 0,0,0);
          Cx[mi][nt] = MFMA(ah, BWlo[nt][ks], Cx[mi][nt], 0,0,0);
          Cx[mi][nt] = MFMA(al, BWhi[nt][ks], Cx[mi][nt], 0,0,0);
        }
      }
    }
    #pragma unroll
    for(int mi=0;mi<2;mi++)
      #pragma unroll
      for(int nt=0;nt<2;nt++)
        red2[q][2*m2+mi][nt][lane] = Cx[mi][nt];
  };

  // ---- one GRU cell (round-6 skeleton) ----
  auto run_cell = [&](const unsigned* hb, unsigned* hw, const f32x4 (&xgf)[2],
                      float (&on)[4]){
    int b0 = (2*m2+0)*16 + col, b1 = (2*m2+1)*16 + col;
    const void* a0 = (const char*)(hb + (size_t)b0*HH + q*128 + lg*8);
    const void* a1 = (const char*)(hb + (size_t)b1*HH + q*128 + lg*8);
    uint4 g00,g01,g02,g03,g04,g05,g06,g07,g10,g11,g12,g13,g14,g15,g16,g17;
    LD16W(g00,g01,g02,g03,g04,g05,g06,g07,
          g10,g11,g12,g13,g14,g15,g16,g17, a0, a1);
    __builtin_amdgcn_sched_barrier(0);

    f32x4 Ch[2][2];
    #pragma unroll
    for(int mi=0;mi<2;mi++){ Ch[mi][0]=(f32x4){0,0,0,0}; Ch[mi][1]=(f32x4){0,0,0,0}; }
    {
      bf16x8 ah, al;
      unpackg(g00,g01,ah,al);
      #pragma unroll
      for(int nt=0;nt<2;nt++){ Ch[0][nt]=MFMA(ah,BUhi[nt][0],Ch[0][nt],0,0,0); Ch[0][nt]=MFMA(ah,BUlo[nt][0],Ch[0][nt],0,0,0); Ch[0][nt]=MFMA(al,BUhi[nt][0],Ch[0][nt],0,0,0); }
      unpackg(g02,g03,ah,al);
      #pragma unroll
      for(int nt=0;nt<2;nt++){ Ch[0][nt]=MFMA(ah,BUhi[nt][1],Ch[0][nt],0,0,0); Ch[0][nt]=MFMA(ah,BUlo[nt][1],Ch[0][nt],0,0,0); Ch[0][nt]=MFMA(al,BUhi[nt][1],Ch[0][nt],0,0,0); }
      unpackg(g04,g05,ah,al);
      #pragma unroll
      for(int nt=0;nt<2;nt++){ Ch[0][nt]=MFMA(ah,BUhi[nt][2],Ch[0][nt],0,0,0); Ch[0][nt]=MFMA(ah,BUlo[nt][2],Ch[0][nt],0,0,0); Ch[0][nt]=MFMA(al,BUhi[nt][2],Ch[0][nt],0,0,0); }
      unpackg(g06,g07,ah,al);
      #pragma unroll
      for(int nt=0;nt<2;nt++){ Ch[0][nt]=MFMA(ah,BUhi[nt][3],Ch[0][nt],0,0,0); Ch[0][nt]=MFMA(ah,BUlo[nt][3],Ch[0][nt],0,0,0); Ch[0][nt]=MFMA(al,BUhi[nt][3],Ch[0][nt],0,0,0); }
      unpackg(g10,g11,ah,al);
      #pragma unroll
      for(int nt=0;nt<2;nt++){ Ch[1][nt]=MFMA(ah,BUhi[nt][0],Ch[1][nt],0,0,0); Ch[1][nt]=MFMA(ah,BUlo[nt][0],Ch[1][nt],0,0,0); Ch[1][nt]=MFMA(al,BUhi[nt][0],Ch[1][nt],0,0,0); }
      unpackg(g12,g13,ah,al);
      #pragma unroll
      for(int nt=0;nt<2;nt++){ Ch[1][nt]=MFMA(ah,BUhi[nt][1],Ch[1][nt],0,0,0); Ch[1][nt]=MFMA(ah,BUlo[nt][1],Ch[1][nt],0,0,0); Ch[1][nt]=MFMA(al,BUhi[nt][1],Ch[1][nt],0,0,0); }
      unpackg(g14,g15,ah,al);
      #pragma unroll
      for(int nt=0;nt<2;nt++){ Ch[1][nt]=MFMA(ah,BUhi[nt][2],Ch[1][nt],0,0,0); Ch[1][nt]=MFMA(ah,BUlo[nt][2],Ch[1][nt],0,0,0); Ch[1][nt]=MFMA(al,BUhi[nt][2],Ch[1][nt],0,0,0); }
      unpackg(g16,g17,ah,al);
      #pragma unroll
      for(int nt=0;nt<2;nt++){ Ch[1][nt]=MFMA(ah,BUhi[nt][3],Ch[1][nt],0,0,0); Ch[1][nt]=MFMA(ah,BUlo[nt][3],Ch[1][nt],0,0,0); Ch[1][nt]=MFMA(al,BUhi[nt][3],Ch[1][nt],0,0,0); }
    }
    #pragma unroll
    for(int mi=0;mi<2;mi++)
      #pragma unroll
      for(int nt=0;nt<2;nt++)
        red[q][2*m2+mi][nt][lane] = Ch[mi][nt];
    __syncthreads();
    if(u < 4){
      const int w = u;
      f32x4 hgf[2];
      #pragma unroll
      for(int nt=0; nt<2; nt++)
        hgf[nt] = red[0][w][nt][lane] + red[1][w][nt][lane]
                + red[2][w][nt][lane] + red[3][w][nt][lane];
      float p0[4], p0s[4];
      #pragma unroll
      for(int r=0;r<4;r++) p0[r] = xgf[0][r] + hgf[0][r] + bsum0;
      #pragma unroll
      for(int r=0;r<4;r++) p0s[r] = __shfl_xor(p0[r], 8, 64);
      if(col < 8){
        #pragma unroll
        for(int r=0;r<4;r++){
          int b = w*16 + lg*4 + r;
          float rg = __builtin_amdgcn_rcpf(1.f + __expf(-p0[r]));
          float ug = __builtin_amdgcn_rcpf(1.f + __expf(-p0s[r]));
          float hn = hgf[1][r] + bun;
          float z  = xgf[1][r] + bwn + rg*hn;
          z = fminf(fmaxf(z, -15.f), 15.f);
          float e  = __expf(2.f*z);
          float nn = (e - 1.f) * __builtin_amdgcn_rcpf(e + 1.f);   // tanh(z)
          float hnew = ug*hreg[r] + (1.f - ug)*nn;
          hreg[r] = hnew;
          on[r]   = hnew;
          unsigned short h16 = f2bf(hnew);
          unsigned short l16 = f2bf(hnew - bf2f(h16));
          __hip_atomic_store(&hw[(size_t)b*HH + j0 + col],
                             ((unsigned)h16 << 16) | (unsigned)l16,
                             __ATOMIC_RELAXED, __HIP_MEMORY_SCOPE_AGENT);
        }
      }
    }
    bar++;
    __syncthreads();   // per-wave vmcnt(0) drain: all h-stores at LLC before flag
    if(tid == 0)
      __hip_atomic_store(&flags[bid], bar, __ATOMIC_RELAXED, __HIP_MEMORY_SCOPE_AGENT);
  };

  // ---- relaxed barrier wait: lane i watches flags[i] ----
  auto poll = [&](){
    unsigned tgt = bar;
    while(true){
      unsigned f = __hip_atomic_load(&flags[lane], __ATOMIC_RELAXED, __HIP_MEMORY_SCOPE_AGENT);
      if(__all((int)(f >= tgt))) break;
      __builtin_amdgcn_s_sleep(1);
    }
    __builtin_amdgcn_sched_barrier(0);
    asm volatile("" ::: "memory");
  };

  unsigned* hb0 = hbuf;
  unsigned* hb1 = hbuf + (size_t)BB*HH;

  f32x4 xgf[2] = {(f32x4){0,0,0,0},(f32x4){0,0,0,0}};
  f32x4 xgn[2] = {(f32x4){0,0,0,0},(f32x4){0,0,0,0}};
  float on0[4] = {0,0,0,0}, on1[4] = {0,0,0,0};

  // prologue: stage x(0), compute xg(0)
  stage_x(0);
  __syncthreads();            // drains global_load_lds (vmcnt) + block barrier
  xg_partials();
  __syncthreads();
  if(u < 4){
    #pragma unroll
    for(int nt=0; nt<2; nt++)
      xgf[nt] = red2[0][u][nt][lane] + red2[1][u][nt][lane]
              + red2[2][u][nt][lane] + red2[3][u][nt][lane];
  }

  for(int t=0; t<TT; t++){
    // ---- even cell: read buf0, write buf1 ----
    run_cell(hb0, hb1, xgf, on0);
    // stage x(t+1): issued in publish/poll dead time; completed by the odd
    // cell's LD16W vmcnt(0) + syncthreads, consumed at xg_partials below
    if(t+1 < TT) stage_x(t+1);
    if(u < 4 && col < 8){
      #pragma unroll
      for(int r=0;r<4;r++){
        int b = u*16 + lg*4 + r;
        out[((size_t)(2*t)*BB + b)*HH + j0 + col] = on0[r];
      }
    }
    poll();
    // ---- odd cell: read buf1, write buf0 (same xg) ----
    run_cell(hb1, hb0, xgf, on1);
    if(u < 4 && col < 8){
      #pragma unroll
      for(int r=0;r<4;r++){
        int b = u*16 + lg*4 + r;
        out[((size_t)(2*t+1)*BB + b)*HH + j0 + col] = on1[r];
      }
    }
    // xg(t+1) from LDS — overlaps odd-cell flag propagation
    if(t+1 < TT){
      xg_partials();
      __syncthreads();
      if(u < 4){
        #pragma unroll
        for(int nt=0; nt<2; nt++)
          xgn[nt] = red2[0][u][nt][lane] + red2[1][u][nt][lane]
                  + red2[2][u][nt][lane] + red2[3][u][nt][lane];
      }
    }
    poll();
    xgf[0] = xgn[0]; xgf[1] = xgn[1];
  }
}

extern "C" void kernel_launch(void* const* d_in, const int* in_sizes, int n_in,
                              void* d_out, int out_size, void* d_ws, size_t ws_size,
                              hipStream_t stream) {
  const float* x  = (const float*)d_in[0];
  const float* Wm = (const float*)d_in[1];
  const float* bW = (const float*)d_in[2];
  const float* Um = (const float*)d_in[3];
  const float* bU = (const float*)d_in[4];
  float* out = (float*)d_out;

  // ws layout: hbuf[2][64][512] u32 (256 KB) + flags[64] u32
  unsigned* hbuf  = (unsigned*)d_ws;
  unsigned* flags = (unsigned*)((char*)d_ws + 2*BB*HH*sizeof(unsigned));
  (void)hipMemsetAsync(d_ws, 0, 2*BB*HH*sizeof(unsigned) + 256, stream);

  gru_scan<<<NBLK, 512, 0, stream>>>(x, Wm, bW, Um, bU, out, hbuf, flags);
}

// Round 13
// 4080.136 us; speedup vs baseline: 1.8958x; 1.4959x over previous
//
#include <hip/hip_runtime.h>
#include <stdint.h>

#define BB   64
#define TT   512
#define KIN  256
#define HH   512
#define JGN  16     // j-groups: 32 cols each
#define BGN  4      // independent batch groups: 16 rows each
#define NJ2  32
#define NB   16
#define XPAD 260

typedef short bf16x8 __attribute__((ext_vector_type(8)));
typedef float f32x4  __attribute__((ext_vector_type(4)));

union U16x8 { unsigned short s[8]; bf16x8 v; };
union FU    { float f; unsigned u; };

__device__ __forceinline__ unsigned short f2bf(float f){
  FU v; v.f = f;
  unsigned r = v.u + 0x7fffu + ((v.u >> 16) & 1u);   // RNE
  return (unsigned short)(r >> 16);
}
__device__ __forceinline__ float bf2f(unsigned short s){
  FU v; v.u = ((unsigned)s) << 16; return v.f;
}
// 8 consecutive f32 -> split bf16 hi/lo fragments
__device__ __forceinline__ void split8(const float* p, bf16x8& hi, bf16x8& lo){
  float4 a = ((const float4*)p)[0];
  float4 b = ((const float4*)p)[1];
  float f[8] = {a.x,a.y,a.z,a.w,b.x,b.y,b.z,b.w};
  U16x8 h,l;
  #pragma unroll
  for(int i=0;i<8;i++){
    unsigned short hb = f2bf(f[i]);
    l.s[i] = f2bf(f[i] - bf2f(hb));
    h.s[i] = hb;
  }
  hi = h.v; lo = l.v;
}
// two uint4 (8 packed u32, bf16hi|bf16lo) -> hi/lo fragments
__device__ __forceinline__ void unpackg(uint4 A, uint4 B, bf16x8& hi, bf16x8& lo){
  unsigned wv[8] = {A.x,A.y,A.z,A.w,B.x,B.y,B.z,B.w};
  U16x8 h,l;
  #pragma unroll
  for(int j=0;j<8;j++){
    h.s[j] = (unsigned short)(wv[j] >> 16);
    l.s[j] = (unsigned short)(wv[j] & 0xffffu);
  }
  hi = h.v; lo = l.v;
}

#define MFMA __builtin_amdgcn_mfma_f32_16x16x32_bf16

// SELF-CONTAINED coherent load: 4 x dwordx4 sc1 + vmcnt(0) in ONE asm block.
// Covers h[row=col][k: wave-slice 64] = 16 packed u32 (offsets 0,16,128,144).
#define LD4W(Q0,Q1,Q2,Q3, BASE) \
  asm volatile( \
    "global_load_dwordx4 %0, %4, off sc1\n\t" \
    "global_load_dwordx4 %1, %4, off offset:16 sc1\n\t" \
    "global_load_dwordx4 %2, %4, off offset:128 sc1\n\t" \
    "global_load_dwordx4 %3, %4, off offset:144 sc1\n\t" \
    "s_waitcnt vmcnt(0)" \
    : "=&v"(Q0),"=&v"(Q1),"=&v"(Q2),"=&v"(Q3) \
    : "v"(BASE) : "memory")

__global__ __launch_bounds__(512, 1) void gru_scan(
    const float* __restrict__ x,  const float* __restrict__ Wm,
    const float* __restrict__ bW, const float* __restrict__ Um,
    const float* __restrict__ bU, float* __restrict__ out,
    unsigned* __restrict__ hbuf,  unsigned* __restrict__ flags)
{
  __shared__ f32x4 red [8][6][64];   // h partials  [wave][ntile][lane] 48 KB
  __shared__ f32x4 red2[8][6][64];   // xg partials 48 KB
  __shared__ float xlds[NB][XPAD];   // x(t) rows for this b-slice (16.6 KB)

  const int tid  = threadIdx.x;
  const int u    = tid >> 6;        // wave 0..7 = K-eighth
  const int lane = tid & 63;
  const int col  = lane & 15;
  const int lg   = lane >> 4;
  const int bid  = blockIdx.x;
  const int bg   = bid >> 4;        // batch group 0..3 (independent chains)
  const int jg   = bid & 15;        // j-group 0..15
  const int j0   = jg * NJ2;
  const int b0g  = bg * NB;         // global batch base

  // ---- persistent U/W fragments for K-slice u (split bf16, registers) ----
  // 6 N-tiles cover 96 gate rows (3 gates x 32 j) -- no padding waste.
  bf16x8 BUhi[6][2], BUlo[6][2], BWhi[6], BWlo[6];
  #pragma unroll
  for(int nt=0; nt<6; nt++){
    int rl   = nt*16 + col;          // local gate row 0..95
    int g    = rl >> 5, jj = rl & 31;
    int grow = g*HH + j0 + jj;       // row in [3H]
    #pragma unroll
    for(int ks=0; ks<2; ks++){
      int kb = u*64 + ks*32 + lg*8;
      split8(Um + (size_t)grow*HH + kb, BUhi[nt][ks], BUlo[nt][ks]);
    }
    int kbw = u*32 + lg*8;
    split8(Wm + (size_t)grow*KIN + kbw, BWhi[nt], BWlo[nt]);
  }

  // ---- biases for gate lanes (gate wave w=u<2 owns j = w*16+col) ----
  float bsr, bsu, bwn, bun;
  {
    int jl = (u & 1)*16 + col;       // valid for all waves; used by u<2
    int r0 = j0 + jl;
    bsr = bW[r0]        + bU[r0];
    bsu = bW[HH + r0]   + bU[HH + r0];
    bwn = bW[2*HH + r0];
    bun = bU[2*HH + r0];
  }

  float hreg[4] = {0.f,0.f,0.f,0.f};

  // ---- stage x(tt) rows [b0g, b0g+16) into LDS (per-lane global src!) ----
  auto stage_x = [&](int tt){
    #pragma unroll
    for(int i=0; i<2; i++){
      int bl = u*2 + i;
      const float* gp = x + ((size_t)(b0g + bl)*TT + tt)*KIN + lane*4;
      __builtin_amdgcn_global_load_lds(
        (const __attribute__((address_space(1))) unsigned*)(const void*)gp,
        (__attribute__((address_space(3))) unsigned*)(void*)&xlds[bl][0],
        16, 0, 0);
    }
  };

  // ---- xg partials from LDS x (18 MFMA/wave) -> red2 ----
  auto xg_partials = [&](){
    f32x4 Cx[6];
    #pragma unroll
    for(int nt=0;nt<6;nt++) Cx[nt]=(f32x4){0,0,0,0};
    bf16x8 ah, al;
    split8(&xlds[col][u*32 + lg*8], ah, al);
    #pragma unroll
    for(int nt=0; nt<6; nt++){
      Cx[nt] = MFMA(ah, BWhi[nt], Cx[nt], 0,0,0);
      Cx[nt] = MFMA(ah, BWlo[nt], Cx[nt], 0,0,0);
      Cx[nt] = MFMA(al, BWhi[nt], Cx[nt], 0,0,0);
    }
    #pragma unroll
    for(int nt=0;nt<6;nt++) red2[u][nt][lane] = Cx[nt];
  };

  // ---- gate-wave reduce of red2 -> xg[3] (r,u,n) ----
  auto xg_reduce = [&](f32x4 (&xg)[3]){
    #pragma unroll
    for(int gi=0; gi<3; gi++){
      int nt = gi*2 + u;             // wave 0: nt 0,2,4 (j 0..15); wave 1: 1,3,5
      f32x4 s = red2[0][nt][lane];
      #pragma unroll
      for(int pw=1; pw<8; pw++) s += red2[pw][nt][lane];
      xg[gi] = s;
    }
  };

  // ---- one GRU cell ----
  auto run_cell = [&](const unsigned* hb, unsigned* hw, int cell,
                      const f32x4 (&xgf)[3], float (&on)[4]){
    // coherent h-load: row = col (batch), k-slice u*64, one exposure
    const void* a0 = (const char*)(hb + (size_t)(b0g + col)*HH + u*64 + lg*8);
    uint4 q0,q1,q2,q3;
    LD4W(q0,q1,q2,q3, a0);
    __builtin_amdgcn_sched_barrier(0);

    f32x4 Ch[6];
    #pragma unroll
    for(int nt=0;nt<6;nt++) Ch[nt]=(f32x4){0,0,0,0};
    {
      bf16x8 ah, al;
      unpackg(q0,q1,ah,al);          // ks = 0
      #pragma unroll
      for(int nt=0; nt<6; nt++){
        Ch[nt] = MFMA(ah, BUhi[nt][0], Ch[nt], 0,0,0);
        Ch[nt] = MFMA(ah, BUlo[nt][0], Ch[nt], 0,0,0);
        Ch[nt] = MFMA(al, BUhi[nt][0], Ch[nt], 0,0,0);
      }
      unpackg(q2,q3,ah,al);          // ks = 1
      #pragma unroll
      for(int nt=0; nt<6; nt++){
        Ch[nt] = MFMA(ah, BUhi[nt][1], Ch[nt], 0,0,0);
        Ch[nt] = MFMA(ah, BUlo[nt][1], Ch[nt], 0,0,0);
        Ch[nt] = MFMA(al, BUhi[nt][1], Ch[nt], 0,0,0);
      }
    }
    #pragma unroll
    for(int nt=0;nt<6;nt++) red[u][nt][lane] = Ch[nt];
    __syncthreads();

    if(u < 2){
      f32x4 hg[3];
      #pragma unroll
      for(int gi=0; gi<3; gi++){
        int nt = gi*2 + u;
        f32x4 s = red[0][nt][lane];
        #pragma unroll
        for(int pw=1; pw<8; pw++) s += red[pw][nt][lane];
        hg[gi] = s;
      }
      #pragma unroll
      for(int r=0;r<4;r++){
        float pr = xgf[0][r] + hg[0][r] + bsr;
        float pu = xgf[1][r] + hg[1][r] + bsu;
        float rg = __builtin_amdgcn_rcpf(1.f + __expf(-pr));
        float ug = __builtin_amdgcn_rcpf(1.f + __expf(-pu));
        float hn = hg[2][r] + bun;
        float z  = xgf[2][r] + bwn + rg*hn;
        z = fminf(fmaxf(z, -15.f), 15.f);
        float e  = __expf(2.f*z);
        float nn = (e - 1.f) * __builtin_amdgcn_rcpf(e + 1.f);   // tanh(z)
        float hnew = ug*hreg[r] + (1.f - ug)*nn;
        hreg[r] = hnew;
        on[r]   = hnew;
        unsigned short h16 = f2bf(hnew);
        unsigned short l16 = f2bf(hnew - bf2f(h16));
        __hip_atomic_store(&hw[(size_t)(b0g + lg*4 + r)*HH + j0 + u*16 + col],
                           ((unsigned)h16 << 16) | (unsigned)l16,
                           __ATOMIC_RELAXED, __HIP_MEMORY_SCOPE_AGENT);
      }
    }
    __syncthreads();   // every wave drains vmcnt -> all h-stores at LLC
    if(tid == 0)
      __hip_atomic_store(&flags[bid], (unsigned)cell + 1u,
                         __ATOMIC_RELAXED, __HIP_MEMORY_SCOPE_AGENT);
  };

  // ---- poll own group's 16 producer flags ----
  auto poll = [&](int tgt){
    const unsigned* fp = flags + bg*16;
    while(true){
      unsigned f = __hip_atomic_load(&fp[lane & 15], __ATOMIC_RELAXED,
                                     __HIP_MEMORY_SCOPE_AGENT);
      if(__all((int)(f >= (unsigned)tgt))) break;
      __builtin_amdgcn_s_sleep(1);
    }
    __builtin_amdgcn_sched_barrier(0);
    asm volatile("" ::: "memory");
  };

  auto out_store = [&](int cell, const float (&on)[4]){
    if(u < 2){
      #pragma unroll
      for(int r=0;r<4;r++)
        out[((size_t)cell*BB + b0g + lg*4 + r)*HH + j0 + u*16 + col] = on[r];
    }
  };

  unsigned* hb0 = hbuf;
  unsigned* hb1 = hbuf + (size_t)BB*HH;

  f32x4 xgf[3] = {(f32x4){0,0,0,0},(f32x4){0,0,0,0},(f32x4){0,0,0,0}};
  f32x4 xgn[3] = {(f32x4){0,0,0,0},(f32x4){0,0,0,0},(f32x4){0,0,0,0}};
  float on0[4] = {0,0,0,0}, on1[4] = {0,0,0,0};

  // prologue: stage x(0), xg(0)
  stage_x(0);
  __syncthreads();
  xg_partials();
  __syncthreads();
  if(u < 2) xg_reduce(xgf);

  for(int t=0; t<TT; t++){
    // ---- even cell (layer 0): read buf0, write buf1 ----
    run_cell(hb0, hb1, 2*t, xgf, on0);
    if(t+1 < TT) stage_x(t+1);       // issued in publish dead-time
    out_store(2*t, on0);
    poll(2*t + 1);
    // ---- odd cell (layer 1): read buf1, write buf0 ----
    run_cell(hb1, hb0, 2*t + 1, xgf, on1);
    if(t+1 < TT){
      xg_partials();                 // overlaps flag propagation
      __syncthreads();
      if(u < 2) xg_reduce(xgn);
    }
    out_store(2*t + 1, on1);
    if(t+1 < TT) poll(2*t + 2);
    xgf[0] = xgn[0]; xgf[1] = xgn[1]; xgf[2] = xgn[2];
  }
}

extern "C" void kernel_launch(void* const* d_in, const int* in_sizes, int n_in,
                              void* d_out, int out_size, void* d_ws, size_t ws_size,
                              hipStream_t stream) {
  const float* x  = (const float*)d_in[0];
  const float* Wm = (const float*)d_in[1];
  const float* bW = (const float*)d_in[2];
  const float* Um = (const float*)d_in[3];
  const float* bU = (const float*)d_in[4];
  float* out = (float*)d_out;

  // ws layout: hbuf[2][64][512] u32 (256 KB) + flags[64] u32
  unsigned* hbuf  = (unsigned*)d_ws;
  unsigned* flags = (unsigned*)((char*)d_ws + 2*BB*HH*sizeof(unsigned));
  (void)hipMemsetAsync(d_ws, 0, 2*BB*HH*sizeof(unsigned) + 256, stream);

  gru_scan<<<BGN*JGN, 512, 0, stream>>>(x, Wm, bW, Um, bU, out, hbuf, flags);
}